// Round 9
// baseline (3851.108 us; speedup 1.0000x reference)
//
#include <hip/hip_runtime.h>
#include <stdint.h>

// B=1024, T=187, H=256, C=5. Two-stage layer-pipelined RNN across 128 CUs.
// Blocks 0..63  (producer): layer-0 recurrence (Whh0) + input proj of layer-1
//   (Wih1), both weight sets AGPR-resident (128 a-regs). Ships xp1_t as f32
//   C-layout fragments (32 B/thread) through a 4-deep ring in d_ws (L2-sized).
// Blocks 64..127 (consumer): layer-1 recurrence (Whh1, 64 a-regs) + FC.
// Pairing (i, i+64) keeps both on one XCD under round-robin (heuristic only;
// correctness via agent-scope acquire/release tokens). Sync is wave-to-wave:
// the slot layout is tid-matched, so producer wave w feeds consumer wave w.
// Tokens are exact-match (flag == s+1): the harness's 0xAA ws-poison can
// never false-trigger, so no flag initialization is needed.
//
// Why restructure (R5-R8 evidence): dur was pinned at 294-310 us across
// spill volumes 1.7-15 MB and LDS 46-111 KB -> the 64-CU structure's
// per-step floor (96 MFMA/SIMD ~= 1862 cyc + tanh + barrier) was the wall.
// Splitting the 3 matvecs 2:1 over 128 CUs puts the slower stage at
// ~64 MFMA/SIMD/step.

#define Bsz 1024
#define Tt  187
#define Hh  256
#define Cc  5
#define ST  264      // f16 elems per batch-col row (256 + 8 pad)
#define XS  188      // x LDS stride (187 + 1)
#define RDEPTH 4
#define SLOTF  512                    // f32 per wave-slot (64 lanes * 8)
#define NRING  (64 * 8 * RDEPTH)      // total wave-slots (4 MiB of f32)
#define FLSTRIDE 16                   // flag words per (pair,wave): 64 B padded

typedef _Float16 f16x8 __attribute__((ext_vector_type(8)));
typedef __fp16   fp16x2 __attribute__((ext_vector_type(2)));
typedef float    f32x4 __attribute__((ext_vector_type(4)));

__device__ __forceinline__ float tanh_fast(float z) {
    float e = __expf(2.0f * z);
    return 1.0f - 2.0f * __builtin_amdgcn_rcpf(1.0f + e);
}
__device__ __forceinline__ unsigned pk2(float a, float b) {
    union { fp16x2 h; unsigned u; } v;
    v.h = __builtin_amdgcn_cvt_pkrtz(a, b);
    return v.u;
}

__global__ __attribute__((amdgpu_flat_work_group_size(512, 512)))
void rnn_pipe(const float* __restrict__ x,     // [B][T]
              const float* __restrict__ Wih0,  // [H][1]
              const float* __restrict__ Whh0,  // [H][H]
              const float* __restrict__ bih0,
              const float* __restrict__ bhh0,
              const float* __restrict__ Wih1,  // [H][H]
              const float* __restrict__ Whh1,  // [H][H]
              const float* __restrict__ bih1,
              const float* __restrict__ bhh1,
              const float* __restrict__ Wfc,   // [C][H]
              const float* __restrict__ bfc,   // [C]
              float* __restrict__ out,         // [B][C]
              float* __restrict__ ring,
              unsigned* __restrict__ flp,      // producer tokens
              unsigned* __restrict__ flc)      // consumer tokens
{
    __shared__ __align__(16) _Float16 ht[2][16 * ST];
    __shared__ float xs[16 * XS];

    const int tid  = threadIdx.x;
    const int lane = tid & 63;
    const int w    = tid >> 6;          // wave 0..7 -> features [32w, 32w+32)
    const int q    = lane >> 4;
    const int c    = lane & 15;         // batch col within tile
    const int role = blockIdx.x >> 6;   // 0 = producer, 1 = consumer
    const int pi   = blockIdx.x & 63;   // pair index == batch tile
    const int bb   = pi * 16;

    const int rdoff  = c * ST + q * 8;
    const int wroff  = c * ST + 32 * w + 4 * q;
    const int fgbase = (pi * 8 + w) * FLSTRIDE;
    float* slotbase  = ring + (size_t)((pi * 8 + w) * RDEPTH) * SLOTF + lane * 8;

    if (role == 0) {
        // ================= PRODUCER: layer-0 recurrence + Wih1 proj =========
        f16x8 wh0[2][8], wi1[2][8];
        f32x4 b0v[2], b1v[2], wi0v[2];
#pragma unroll
        for (int mt = 0; mt < 2; ++mt) {
            const int fb = 32 * w + 16 * mt;
#pragma unroll
            for (int r = 0; r < 4; ++r) {
                const int f = fb + 4 * q + r;
                b0v[mt][r]  = bih0[f] + bhh0[f];
                b1v[mt][r]  = bih1[f] + bhh1[f];
                wi0v[mt][r] = Wih0[f];
            }
            const int mm = fb + c;
#pragma unroll
            for (int kt = 0; kt < 8; ++kt) {
                const int off = mm * Hh + kt * 32 + q * 8;
                {
                    const float4 a0 = *(const float4*)(Whh0 + off);
                    const float4 a1 = *(const float4*)(Whh0 + off + 4);
                    wh0[mt][kt] = (f16x8){(_Float16)a0.x, (_Float16)a0.y, (_Float16)a0.z, (_Float16)a0.w,
                                          (_Float16)a1.x, (_Float16)a1.y, (_Float16)a1.z, (_Float16)a1.w};
                }
                {
                    const float4 a0 = *(const float4*)(Wih1 + off);
                    const float4 a1 = *(const float4*)(Wih1 + off + 4);
                    wi1[mt][kt] = (f16x8){(_Float16)a0.x, (_Float16)a0.y, (_Float16)a0.z, (_Float16)a0.w,
                                          (_Float16)a1.x, (_Float16)a1.y, (_Float16)a1.z, (_Float16)a1.w};
                }
            }
        }
        asm volatile("" : "+a"(wh0[0][0]), "+a"(wh0[0][1]), "+a"(wh0[0][2]), "+a"(wh0[0][3]),
                          "+a"(wh0[0][4]), "+a"(wh0[0][5]), "+a"(wh0[0][6]), "+a"(wh0[0][7]),
                          "+a"(wh0[1][0]), "+a"(wh0[1][1]), "+a"(wh0[1][2]), "+a"(wh0[1][3]),
                          "+a"(wh0[1][4]), "+a"(wh0[1][5]), "+a"(wh0[1][6]), "+a"(wh0[1][7]));
        asm volatile("" : "+a"(wi1[0][0]), "+a"(wi1[0][1]), "+a"(wi1[0][2]), "+a"(wi1[0][3]),
                          "+a"(wi1[0][4]), "+a"(wi1[0][5]), "+a"(wi1[0][6]), "+a"(wi1[0][7]),
                          "+a"(wi1[1][0]), "+a"(wi1[1][1]), "+a"(wi1[1][2]), "+a"(wi1[1][3]),
                          "+a"(wi1[1][4]), "+a"(wi1[1][5]), "+a"(wi1[1][6]), "+a"(wi1[1][7]));

        for (int i2 = tid; i2 < 16 * Tt; i2 += 512) {
            const int b = i2 / Tt, t = i2 - b * Tt;
            xs[b * XS + t] = x[(bb + b) * Tt + t];
        }
        for (int i2 = tid; i2 < 16 * Hh; i2 += 512) {
            const int b = i2 >> 8, f = i2 & 255;
            const float xv0 = x[(bb + b) * Tt];
            ht[0][b * ST + f] = (_Float16)tanh_fast(xv0 * Wih0[f] + bih0[f] + bhh0[f]);
        }
        __syncthreads();

#pragma unroll 1
        for (int s = 0; s < Tt; ++s) {
            const int cur = s & 1, nxt = cur ^ 1, m = s & (RDEPTH - 1);
            const _Float16* B0p = &ht[cur][rdoff];
            int sn = s + 1; if (sn >= Tt) sn = Tt - 1;
            const float xv = xs[c * XS + sn];

            f32x4 ai[2], ah0[2];
            ai[0] = b1v[0]; ai[1] = b1v[1]; ah0[0] = b0v[0]; ah0[1] = b0v[1];
#pragma unroll
            for (int kt = 0; kt < 8; ++kt) {
                const f16x8 B = *(const f16x8*)(B0p + kt * 32);
                ai[0]  = __builtin_amdgcn_mfma_f32_16x16x32_f16(wi1[0][kt], B, ai[0],  0, 0, 0);
                ai[1]  = __builtin_amdgcn_mfma_f32_16x16x32_f16(wi1[1][kt], B, ai[1],  0, 0, 0);
                ah0[0] = __builtin_amdgcn_mfma_f32_16x16x32_f16(wh0[0][kt], B, ah0[0], 0, 0, 0);
                ah0[1] = __builtin_amdgcn_mfma_f32_16x16x32_f16(wh0[1][kt], B, ah0[1], 0, 0, 0);
            }

            // ---- ship xp1_s (wave-to-wave ring) ----
            if (s >= RDEPTH) {
                const unsigned tgt = (unsigned)(s + 1 - RDEPTH);
                int gd = 0;
                while (__hip_atomic_load(&flc[fgbase + m], __ATOMIC_ACQUIRE,
                                         __HIP_MEMORY_SCOPE_AGENT) != tgt)
                    if (++gd > (1 << 22)) break;
            }
            float* sp = slotbase + m * SLOTF;
            *(f32x4*)sp       = ai[0];
            *(f32x4*)(sp + 4) = ai[1];
            if (lane == 0)
                __hip_atomic_store(&flp[fgbase + m], (unsigned)(s + 1),
                                   __ATOMIC_RELEASE, __HIP_MEMORY_SCOPE_AGENT);

            // ---- h0_{s+1} = tanh(ah0 + x_{s+1} * wih0) ----
#pragma unroll
            for (int mt = 0; mt < 2; ++mt) {
                const float t0 = tanh_fast(ah0[mt][0] + xv * wi0v[mt][0]);
                const float t1 = tanh_fast(ah0[mt][1] + xv * wi0v[mt][1]);
                const float t2 = tanh_fast(ah0[mt][2] + xv * wi0v[mt][2]);
                const float t3 = tanh_fast(ah0[mt][3] + xv * wi0v[mt][3]);
                *(uint2*)(&ht[nxt][wroff + 16 * mt]) = make_uint2(pk2(t0, t1), pk2(t2, t3));
            }
            __syncthreads();
        }
    } else {
        // ================= CONSUMER: layer-1 recurrence + FC ================
        f16x8 wh1[2][8];
#pragma unroll
        for (int mt = 0; mt < 2; ++mt) {
            const int fb = 32 * w + 16 * mt;
            const int mm = fb + c;
#pragma unroll
            for (int kt = 0; kt < 8; ++kt) {
                const int off = mm * Hh + kt * 32 + q * 8;
                const float4 a0 = *(const float4*)(Whh1 + off);
                const float4 a1 = *(const float4*)(Whh1 + off + 4);
                wh1[mt][kt] = (f16x8){(_Float16)a0.x, (_Float16)a0.y, (_Float16)a0.z, (_Float16)a0.w,
                                      (_Float16)a1.x, (_Float16)a1.y, (_Float16)a1.z, (_Float16)a1.w};
            }
        }
        asm volatile("" : "+a"(wh1[0][0]), "+a"(wh1[0][1]), "+a"(wh1[0][2]), "+a"(wh1[0][3]),
                          "+a"(wh1[0][4]), "+a"(wh1[0][5]), "+a"(wh1[0][6]), "+a"(wh1[0][7]),
                          "+a"(wh1[1][0]), "+a"(wh1[1][1]), "+a"(wh1[1][2]), "+a"(wh1[1][3]),
                          "+a"(wh1[1][4]), "+a"(wh1[1][5]), "+a"(wh1[1][6]), "+a"(wh1[1][7]));

        for (int i2 = tid; i2 < 16 * ST; i2 += 512)   // zero the s=0 "previous" buffer
            ht[1][i2] = (_Float16)0.f;
        __syncthreads();

#pragma unroll 1
        for (int s = 0; s < Tt; ++s) {
            const int cur = s & 1, nxt = cur ^ 1, m = s & (RDEPTH - 1);
            const unsigned tgt = (unsigned)(s + 1);
            int gd = 0;
            while (__hip_atomic_load(&flp[fgbase + m], __ATOMIC_ACQUIRE,
                                     __HIP_MEMORY_SCOPE_AGENT) != tgt)
                if (++gd > (1 << 22)) break;
            const float* sp = slotbase + m * SLOTF;
            const f32x4 xq0 = *(const f32x4*)sp;
            const f32x4 xq1 = *(const f32x4*)(sp + 4);

            const _Float16* B1p = &ht[nxt][rdoff];
            f32x4 ah1[2];
            ah1[0] = (f32x4){0.f, 0.f, 0.f, 0.f};
            ah1[1] = (f32x4){0.f, 0.f, 0.f, 0.f};
#pragma unroll
            for (int kt = 0; kt < 8; ++kt) {
                const f16x8 B = *(const f16x8*)(B1p + kt * 32);
                ah1[0] = __builtin_amdgcn_mfma_f32_16x16x32_f16(wh1[0][kt], B, ah1[0], 0, 0, 0);
                ah1[1] = __builtin_amdgcn_mfma_f32_16x16x32_f16(wh1[1][kt], B, ah1[1], 0, 0, 0);
            }
            {
                const float t0 = tanh_fast(xq0[0] + ah1[0][0]);
                const float t1 = tanh_fast(xq0[1] + ah1[0][1]);
                const float t2 = tanh_fast(xq0[2] + ah1[0][2]);
                const float t3 = tanh_fast(xq0[3] + ah1[0][3]);
                *(uint2*)(&ht[cur][wroff]) = make_uint2(pk2(t0, t1), pk2(t2, t3));
            }
            {
                const float t0 = tanh_fast(xq1[0] + ah1[1][0]);
                const float t1 = tanh_fast(xq1[1] + ah1[1][1]);
                const float t2 = tanh_fast(xq1[2] + ah1[1][2]);
                const float t3 = tanh_fast(xq1[3] + ah1[1][3]);
                *(uint2*)(&ht[cur][wroff + 16]) = make_uint2(pk2(t0, t1), pk2(t2, t3));
            }
            if (lane == 0)   // release: ordered after the xq loads + tanh consumption
                __hip_atomic_store(&flc[fgbase + m], tgt,
                                   __ATOMIC_RELEASE, __HIP_MEMORY_SCOPE_AGENT);
            __syncthreads();
        }

        // ---- FC epilogue ----
        if (tid < 16 * Cc) {
            const int b = tid / Cc, cls = tid - Cc * (tid / Cc);
            const _Float16* h = &ht[(Tt - 1) & 1][b * ST];
            float acc = bfc[cls];
            for (int k = 0; k < Hh; ++k)
                acc += (float)h[k] * Wfc[cls * Hh + k];
            out[(bb + b) * Cc + cls] = acc;
        }
    }
}

extern "C" void kernel_launch(void* const* d_in, const int* in_sizes, int n_in,
                              void* d_out, int out_size, void* d_ws, size_t ws_size,
                              hipStream_t stream) {
    float*    ring = (float*)d_ws;
    unsigned* flp  = (unsigned*)((char*)d_ws + (size_t)NRING * SLOTF * 4);
    unsigned* flc  = flp + 64 * 8 * FLSTRIDE;
    rnn_pipe<<<dim3(128), dim3(512), 0, stream>>>(
        (const float*)d_in[0],  // x
        (const float*)d_in[1],  // W_ih0
        (const float*)d_in[2],  // W_hh0
        (const float*)d_in[3],  // b_ih0
        (const float*)d_in[4],  // b_hh0
        (const float*)d_in[5],  // W_ih1
        (const float*)d_in[6],  // W_hh1
        (const float*)d_in[7],  // b_ih1
        (const float*)d_in[8],  // b_hh1
        (const float*)d_in[9],  // W_fc
        (const float*)d_in[10], // b_fc
        (float*)d_out, ring, flp, flc);
}

// Round 10
// 458.662 us; speedup vs baseline: 8.3964x; 8.3964x over previous
//
#include <hip/hip_runtime.h>
#include <stdint.h>

// B=1024, T=187, H=256, C=5. Fully-fused persistent 2-layer RNN + FC.
// Transposed recurrence: ht = h^T in LDS as [batch col][feature]; state is
// the MFMA B-operand, weights (A-operand, f16 fragments) are register-
// resident. 64 blocks x 16 batch cols.
//
// R10 restructure: 4 waves x 64-feature slices (256 threads) instead of
// 8 x 32. Rationale (R7/R8 counters): every wave reads the IDENTICAL
// B-operand state fragments, so state DS traffic scales with wave count;
// at 8 waves the DS pipe (~2300 cyc/CU/step) exceeded the MFMA floor
// (1862 cyc). 4 waves -> 96 ds_read_b128/CU/step (~1150 cyc), DS now
// under the floor. Budget: 256-thread blocks get v=256 granted (R1) on
// top of a<=256 -> wh0+wi1 pinned in 256 AGPRs (per-mt pins to limit
// prologue pressure), wh1 kt0-5 in VGPRs, kt6-7 in per-wave LDS.
// R9 lesson (not repeated): cross-CU handshakes cost ~us on MI355X
// (non-coherent per-XCD L2s) — everything stays in one block per tile.

#define Bsz 1024
#define Tt  187
#define Hh  256
#define Cc  5
#define ST  264      // f16 elems per batch-col row (256 + 8 pad)
#define XS  188      // x LDS stride (187 + 1)

typedef _Float16 f16x8 __attribute__((ext_vector_type(8)));
typedef __fp16   fp16x2 __attribute__((ext_vector_type(2)));
typedef float    f32x4 __attribute__((ext_vector_type(4)));

__device__ __forceinline__ float tanh_fast(float z) {
    float e = __expf(2.0f * z);
    return 1.0f - 2.0f * __builtin_amdgcn_rcpf(1.0f + e);
}
__device__ __forceinline__ unsigned pk2(float a, float b) {
    union { fp16x2 h; unsigned u; } v;
    v.h = __builtin_amdgcn_cvt_pkrtz(a, b);
    return v.u;
}
__device__ __forceinline__ f16x8 ld_frag(const float* p) {
    const float4 a0 = *(const float4*)p;
    const float4 a1 = *(const float4*)(p + 4);
    return (f16x8){(_Float16)a0.x, (_Float16)a0.y, (_Float16)a0.z, (_Float16)a0.w,
                   (_Float16)a1.x, (_Float16)a1.y, (_Float16)a1.z, (_Float16)a1.w};
}

__global__ __launch_bounds__(256, 1)
void rnn_fused(const float* __restrict__ x,     // [B][T]
               const float* __restrict__ Wih0,  // [H][1]
               const float* __restrict__ Whh0,  // [H][H]
               const float* __restrict__ bih0,
               const float* __restrict__ bhh0,
               const float* __restrict__ Wih1,  // [H][H]
               const float* __restrict__ Whh1,  // [H][H]
               const float* __restrict__ bih1,
               const float* __restrict__ bhh1,
               const float* __restrict__ Wfc,   // [C][H]
               const float* __restrict__ bfc,   // [C]
               float* __restrict__ out)         // [B][C]
{
    __shared__ __align__(16) _Float16 ht0[2][16 * ST];
    __shared__ __align__(16) _Float16 ht1[2][16 * ST];
    __shared__ float xs[16 * XS];
    __shared__ f16x8 w1lds[4][4][2][64];   // [wave][mt][kt-6][lane], per-wave private (32 KB)

    const int tid  = threadIdx.x;
    const int lane = tid & 63;
    const int w    = tid >> 6;     // wave 0..3 -> features [64w, 64w+64)
    const int q    = lane >> 4;
    const int c    = lane & 15;    // batch col within block
    const int bb   = blockIdx.x * 16;

    // ---- one-time: stage weight A-fragments (f16) ----
    // A-layout: lane (q,c) reg j holds A[m][k=kt*32+q*8+j], row m = fb+c.
    f16x8 wh0[4][8], wi1[4][8], wh1r[4][6];
    f32x4 b0v[4], b1v[4], wi0v[4];   // per (mt,r): feature fb+4q+r (C/D layout)
#pragma unroll
    for (int mt = 0; mt < 4; ++mt) {
        const int fb = 64 * w + 16 * mt;
#pragma unroll
        for (int r = 0; r < 4; ++r) {
            const int f = fb + 4 * q + r;
            b0v[mt][r]  = bih0[f] + bhh0[f];
            b1v[mt][r]  = bih1[f] + bhh1[f];
            wi0v[mt][r] = Wih0[f];
        }
        const int m = fb + c;
#pragma unroll
        for (int kt = 0; kt < 8; ++kt) {
            const int off = m * Hh + kt * 32 + q * 8;
            wh0[mt][kt] = ld_frag(Whh0 + off);
            wi1[mt][kt] = ld_frag(Wih1 + off);
            f16x8 f = ld_frag(Whh1 + off);
            if (kt < 6) wh1r[mt][kt] = f;
            else        w1lds[w][mt][kt - 6][lane] = f;
        }
        // pin this mt-slice of Whh0+Wih1 into AGPRs now (keeps prologue
        // VGPR pressure low; 16 frags = 64 a-regs per mt, 256 total)
        asm volatile("" : "+a"(wh0[mt][0]), "+a"(wh0[mt][1]), "+a"(wh0[mt][2]), "+a"(wh0[mt][3]),
                          "+a"(wh0[mt][4]), "+a"(wh0[mt][5]), "+a"(wh0[mt][6]), "+a"(wh0[mt][7]),
                          "+a"(wi1[mt][0]), "+a"(wi1[mt][1]), "+a"(wi1[mt][2]), "+a"(wi1[mt][3]),
                          "+a"(wi1[mt][4]), "+a"(wi1[mt][5]), "+a"(wi1[mt][6]), "+a"(wi1[mt][7]));
    }

    // ---- init LDS: x tile, ht1 = 0 (both buffers), ht0[0] = state t=0 ----
    for (int i = tid; i < 16 * Tt; i += 256) {
        const int b = i / Tt, t = i - b * Tt;
        xs[b * XS + t] = x[(bb + b) * Tt + t];
    }
    {
        _Float16* z = &ht1[0][0];
        for (int i = tid; i < 2 * 16 * ST; i += 256) z[i] = (_Float16)0.f;
    }
    for (int i = tid; i < 16 * Hh; i += 256) {
        const int b = i >> 8, f = i & 255;
        const float xv0 = x[(bb + b) * Tt];
        ht0[0][b * ST + f] =
            (_Float16)tanh_fast(xv0 * Wih0[f] + bih0[f] + bhh0[f]);
    }
    __syncthreads();

    // B-operand read base: lane (q,c) reg j needs ht[k=kt*32+q*8+j][col c]
    // -> LDS [c][kt*32+q*8], contiguous 16B (ds_read_b128).
    const int rdoff = c * ST + q * 8;
    const int wroff = c * ST + 64 * w + 4 * q;   // D write: [c][fb+4q .. +3]

    // ---- main recurrence, time-skewed:
    // step s: B0 = ht0[s]; produce ht0[s+1] (Whh0) and ht1[s] (Wih1 + Whh1)
#pragma unroll 1
    for (int s = 0; s < Tt; ++s) {
        const int cur = s & 1, nxt = cur ^ 1;
        const _Float16* B0p = &ht0[cur][rdoff];
        const _Float16* B1p = &ht1[nxt][rdoff];   // ht1[s-1]
        int sn = s + 1; if (sn >= Tt) sn = Tt - 1;  // last h0_next unused
        const float xv = xs[c * XS + sn];

        // layer0: ai = Wih1 . ht0 + b1 ; ah0 = Whh0 . ht0 + b0 (shared B-frag)
        f32x4 ai[4], ah0[4];
#pragma unroll
        for (int mt = 0; mt < 4; ++mt) { ai[mt] = b1v[mt]; ah0[mt] = b0v[mt]; }
#pragma unroll
        for (int kt = 0; kt < 8; ++kt) {
            const f16x8 B = *(const f16x8*)(B0p + kt * 32);
#pragma unroll
            for (int mt = 0; mt < 4; ++mt) {
                ai[mt]  = __builtin_amdgcn_mfma_f32_16x16x32_f16(wi1[mt][kt], B, ai[mt],  0, 0, 0);
                ah0[mt] = __builtin_amdgcn_mfma_f32_16x16x32_f16(wh0[mt][kt], B, ah0[mt], 0, 0, 0);
            }
        }
        // ht0[s+1] = tanh(ah0 + x_{s+1} * wih0), pack f16, 8B LDS writes
#pragma unroll
        for (int mt = 0; mt < 4; ++mt) {
            const float t0 = tanh_fast(ah0[mt][0] + xv * wi0v[mt][0]);
            const float t1 = tanh_fast(ah0[mt][1] + xv * wi0v[mt][1]);
            const float t2 = tanh_fast(ah0[mt][2] + xv * wi0v[mt][2]);
            const float t3 = tanh_fast(ah0[mt][3] + xv * wi0v[mt][3]);
            *(uint2*)(&ht0[nxt][wroff + 16 * mt]) = make_uint2(pk2(t0, t1), pk2(t2, t3));
        }

        // layer1: ah1 = Whh1 . ht1[s-1]; kt<6 weights in regs, kt>=6 from LDS
        f32x4 ah1[4];
#pragma unroll
        for (int mt = 0; mt < 4; ++mt) ah1[mt] = (f32x4){0.f, 0.f, 0.f, 0.f};
#pragma unroll
        for (int kt = 0; kt < 6; ++kt) {
            const f16x8 B = *(const f16x8*)(B1p + kt * 32);
#pragma unroll
            for (int mt = 0; mt < 4; ++mt)
                ah1[mt] = __builtin_amdgcn_mfma_f32_16x16x32_f16(wh1r[mt][kt], B, ah1[mt], 0, 0, 0);
        }
#pragma unroll
        for (int kt = 6; kt < 8; ++kt) {
            const f16x8 B = *(const f16x8*)(B1p + kt * 32);
#pragma unroll
            for (int mt = 0; mt < 4; ++mt) {
                const f16x8 A = w1lds[w][mt][kt - 6][lane];
                ah1[mt] = __builtin_amdgcn_mfma_f32_16x16x32_f16(A, B, ah1[mt], 0, 0, 0);
            }
        }
        // ht1[s] = tanh(ai + ah1)
#pragma unroll
        for (int mt = 0; mt < 4; ++mt) {
            const float t0 = tanh_fast(ai[mt][0] + ah1[mt][0]);
            const float t1 = tanh_fast(ai[mt][1] + ah1[mt][1]);
            const float t2 = tanh_fast(ai[mt][2] + ah1[mt][2]);
            const float t3 = tanh_fast(ai[mt][3] + ah1[mt][3]);
            *(uint2*)(&ht1[cur][wroff + 16 * mt]) = make_uint2(pk2(t0, t1), pk2(t2, t3));
        }
        __syncthreads();   // double-buffered: one barrier per step
    }

    // ---- FC epilogue: out[bb+b][cls] = ht1_final[.][b] . Wfc[cls] + bfc ----
    if (tid < 16 * Cc) {
        const int b = tid / Cc, cls = tid - Cc * (tid / Cc);
        const _Float16* h = &ht1[(Tt - 1) & 1][b * ST];
        float acc = bfc[cls];
        for (int k = 0; k < Hh; ++k)
            acc += (float)h[k] * Wfc[cls * Hh + k];
        out[(bb + b) * Cc + cls] = acc;
    }
}

extern "C" void kernel_launch(void* const* d_in, const int* in_sizes, int n_in,
                              void* d_out, int out_size, void* d_ws, size_t ws_size,
                              hipStream_t stream) {
    rnn_fused<<<dim3(Bsz / 16), dim3(256), 0, stream>>>(
        (const float*)d_in[0],  // x
        (const float*)d_in[1],  // W_ih0
        (const float*)d_in[2],  // W_hh0
        (const float*)d_in[3],  // b_ih0
        (const float*)d_in[4],  // b_hh0
        (const float*)d_in[5],  // W_ih1
        (const float*)d_in[6],  // W_hh1
        (const float*)d_in[7],  // b_ih1
        (const float*)d_in[8],  // b_hh1
        (const float*)d_in[9],  // W_fc
        (const float*)d_in[10], // b_fc
        (float*)d_out);
}